// Round 1
// 155.528 us; speedup vs baseline: 1.0692x; 1.0692x over previous
//
#include <hip/hip_runtime.h>
#include <math.h>

#define NBATCH 2
#define HH 1024
#define WW 1024
#define KKER 24
#define KDIM 35
#define NPIX (HH*WW)
#define KSQ (KDIM*KDIM)          // 1225
#define NDA 69                   // da in [-34,34]
#define NCH 7                    // ap-chunks in mk_V (5 rows each)
#define NFR 18                   // stored row freqs m=0..17 (Hermitian half)

// ---- workspace layout (float offsets) ----
#define G_OFF    0                                       // NBATCH*HH*NFR complex
#define SPEC_OFF (G_OFF + NBATCH*HH*NFR*2)               // NBATCH*35*35 complex
#define VP_OFF   (SPEC_OFF + NBATCH*KSQ*2)               // [nb(4)][kc(168)][dai(69)][db(35)] complex
#define V_OFF    (VP_OFF + NBATCH*2*KKER*NCH*NDA*KDIM*2) // [nb][dai][db] complex

__device__ __forceinline__ float2 cmadd(float2 p, float2 w, float2 u) {
    // p*w + u
    return make_float2(fmaf(p.x, w.x, fmaf(-p.y, w.y, u.x)),
                       fmaf(p.x, w.y, fmaf( p.y, w.x, u.y)));
}
__device__ __forceinline__ float sigm(float v) {
    return 1.f / (1.f + expf(-v));
}

// fused: avepool3(zero-pad) + sigmoid + forward DFT along x for m=0..17 (real input:
// G[n,y,-m] = conj(G[n,y,m]), so only half the freqs are computed/stored).
__global__ __launch_bounds__(320) void fwd_rows(const float* __restrict__ mt, float* __restrict__ ws) {
    __shared__ __align__(16) float vs[1024];
    __shared__ float row[1056];          // padded: idx = x + (x>>5) -> kills 4-way bank conflict
    __shared__ float2 twl[1024];
    __shared__ float2 P[16 * NFR];
    int bid = blockIdx.x;            // n*HH + y
    int n = bid >> 10, y = bid & 1023;
    int t = threadIdx.x;
    const float* base = mt + (size_t)n * NPIX;
    if (t < 256) {
        float4 a = ((const float4*)(base + (size_t)y * WW))[t];
        if (y > 0)    { float4 b = ((const float4*)(base + (size_t)(y - 1) * WW))[t];
                        a.x += b.x; a.y += b.y; a.z += b.z; a.w += b.w; }
        if (y < 1023) { float4 b = ((const float4*)(base + (size_t)(y + 1) * WW))[t];
                        a.x += b.x; a.y += b.y; a.z += b.z; a.w += b.w; }
        ((float4*)vs)[t] = a;
    }
    for (int j = t; j < 1024; j += 320) {
        float s, c;
        sincospif(-2.0f * (float)j * (1.0f / 1024.0f), &s, &c);
        twl[j] = make_float2(c, s);      // e^{-2 pi i j / 1024}
    }
    __syncthreads();
    for (int x = t; x < 1024; x += 320) {
        float s = vs[x];
        if (x > 0)    s += vs[x - 1];
        if (x < 1023) s += vs[x + 1];
        s *= (1.0f / 9.0f);
        row[x + (x >> 5)] = sigm(4.0f * (s - 0.5f));
    }
    __syncthreads();
    if (t < 16 * NFR) {
        int q = t / NFR, m = t - q * NFR;   // q in [0,16), m in [0,18)
        float2 cm = twl[m];                 // e^{-2pi i m/1024}
        float ar = 0.f, ai = 0.f;
        #pragma unroll
        for (int sc = 0; sc < 2; ++sc) {
            int xs = q * 64 + sc * 32;
            unsigned j0 = ((unsigned)(m * xs)) & 1023u;
            float2 wv = twl[j0];               // exact resync
            float wr = wv.x, wi = wv.y;
            int rb = xs + (xs >> 5);
            #pragma unroll
            for (int i = 0; i < 32; ++i) {
                float val = row[rb + i];
                ar = fmaf(val, wr, ar);
                ai = fmaf(val, wi, ai);
                float nwr = fmaf(wr, cm.x, -wi * cm.y);
                float nwi = fmaf(wr, cm.y,  wi * cm.x);
                wr = nwr; wi = nwi;
            }
        }
        P[t] = make_float2(ar, ai);
    }
    __syncthreads();
    if (t < NFR) {
        float gr = 0.f, gi = 0.f;
        #pragma unroll
        for (int q = 0; q < 16; ++q) {
            gr += P[q * NFR + t].x;
            gi += P[q * NFR + t].y;
        }
        float2* Gp = (float2*)(ws + G_OFF) + (size_t)(n * HH + y) * NFR + t;
        *Gp = make_float2(gr, gi);
    }
}

// forward DFT along y for the half-plane b>=17; the other half follows by Hermitian
// symmetry of the 2D spectrum of a real image: spec[34-a][34-b] = conj(spec[a][b]).
__global__ __launch_bounds__(320) void fwd_cols(float* __restrict__ ws) {
    __shared__ float2 twl[1024];
    __shared__ float2 P[16 * NFR];
    int bid = blockIdx.x;            // n*KDIM + a
    int n = bid / KDIM, a = bid - n * KDIM;
    int t = threadIdx.x;
    for (int j = t; j < 1024; j += 320) {
        float s, c;
        sincospif(-2.0f * (float)j * (1.0f / 1024.0f), &s, &c);
        twl[j] = make_float2(c, s);
    }
    __syncthreads();
    if (t < 16 * NFR) {
        int g = t / NFR, mb = t - g * NFR;   // g in [0,16) y-chunks, mb = b-17 in [0,18)
        int ma = a - 17;
        int y0 = g * 64;
        const float2* Gp = (const float2*)(ws + G_OFF) + (size_t)n * HH * NFR + mb;
        float ar = 0.f, ai = 0.f;
        for (int i = 0; i < 64; ++i) {
            int y = y0 + i;
            unsigned j = ((unsigned)(ma * y)) & 1023u;
            float2 g2 = Gp[(size_t)y * NFR];
            float2 cc = twl[j];
            ar = fmaf(g2.x, cc.x, ar); ar = fmaf(-g2.y, cc.y, ar);
            ai = fmaf(g2.x, cc.y, ai); ai = fmaf( g2.y, cc.x, ai);
        }
        P[t] = make_float2(ar, ai);
    }
    __syncthreads();
    if (t < NFR) {
        float sr = 0.f, si = 0.f;
        #pragma unroll
        for (int g = 0; g < 16; ++g) { sr += P[g * NFR + t].x; si += P[g * NFR + t].y; }
        float2* Sp = (float2*)(ws + SPEC_OFF) + (size_t)n * KSQ;
        Sp[a * KDIM + (17 + t)] = make_float2(sr, si);
        if (t > 0)
            Sp[(34 - a) * KDIM + (17 - t)] = make_float2(sr, -si);  // Hermitian mirror
    }
}

// 2D autocorrelation, register-tiled sliding window, uniform trips via zero-padded X.
#define VROWS 103   // rows -34..68 (index a+34)
#define VCOLS 43    // cols 0..34 valid, 35..42 zero pad
__global__ __launch_bounds__(384) void mk_V(float* __restrict__ ws,
        const float* __restrict__ kfr, const float* __restrict__ kfi,
        const float* __restrict__ kdr, const float* __restrict__ kdi,
        const float* __restrict__ kfs, const float* __restrict__ kds) {
    __shared__ float2 Xp[VROWS * VCOLS];   // 35.4 KB
    int bid = blockIdx.x;
    int c = bid % NCH; int r = bid / NCH;
    int k = r % KKER; r /= KKER;
    int br = r & 1; int n = r >> 1;
    int t = threadIdx.x;
    for (int i = t; i < VROWS * VCOLS; i += 384) Xp[i] = make_float2(0.f, 0.f);
    __syncthreads();
    const float* kr = (br ? kdr : kfr) + (size_t)k * KSQ;
    const float* ki = (br ? kdi : kfi) + (size_t)k * KSQ;
    const float* sp = ws + SPEC_OFF + (size_t)n * KSQ * 2;
    for (int i = t; i < KSQ; i += 384) {
        int a = i / KDIM, b = i - a * KDIM;
        float srr = sp[2*i], sii = sp[2*i + 1];
        float krr = kr[i], kii = ki[i];
        Xp[(a + 34) * VCOLS + b] = make_float2(srr * krr - sii * kii, srr * kii + sii * krr);
    }
    __syncthreads();
    const float INVN = 0x1p-40f;
    float s = (br ? kds[k] * (0.98f * 0.98f) : kfs[k]) * INVN;
    if (t < NDA * 5) {
        int dbg = t / NDA;            // 5 groups of 8 db
        int dai = t - dbg * NDA;
        int da  = dai - 34;
        int db0 = dbg * 8;
        int nbp = KDIM - db0;         // 35,27,19,11,3
        int ap0 = c * 5;
        int ap1 = ap0 + 5; if (ap1 > KDIM) ap1 = KDIM;
        float2 acc[8];
        #pragma unroll
        for (int j = 0; j < 8; ++j) acc[j] = make_float2(0.f, 0.f);
        for (int ap = ap0; ap < ap1; ++ap) {
            const float2* rx = Xp + (ap + da + 34) * VCOLS + db0;
            const float2* ry = Xp + (ap + 34) * VCOLS;
            float2 w[8];
            #pragma unroll
            for (int j = 0; j < 8; ++j) w[j] = rx[j];
            int bp = 0;
            for (; bp + 8 <= nbp; bp += 8) {
                #pragma unroll
                for (int u = 0; u < 8; ++u) {
                    float2 yv = ry[bp + u];               // wave-broadcast
                    #pragma unroll
                    for (int j = 0; j < 8; ++j) {
                        acc[j].x = fmaf(w[j].x, yv.x, acc[j].x);
                        acc[j].x = fmaf(w[j].y, yv.y, acc[j].x);
                        acc[j].y = fmaf(w[j].y, yv.x, acc[j].y);
                        acc[j].y = fmaf(-w[j].x, yv.y, acc[j].y);
                    }
                    #pragma unroll
                    for (int j = 0; j < 7; ++j) w[j] = w[j + 1];
                    w[7] = rx[bp + u + 8];
                }
            }
            for (; bp < nbp; ++bp) {
                float2 yv = ry[bp];
                #pragma unroll
                for (int j = 0; j < 8; ++j) {
                    acc[j].x = fmaf(w[j].x, yv.x, acc[j].x);
                    acc[j].x = fmaf(w[j].y, yv.y, acc[j].x);
                    acc[j].y = fmaf(w[j].y, yv.x, acc[j].y);
                    acc[j].y = fmaf(-w[j].x, yv.y, acc[j].y);
                }
                #pragma unroll
                for (int j = 0; j < 7; ++j) w[j] = w[j + 1];
                w[7] = rx[bp + 8];
            }
        }
        int nb = n * 2 + br;
        size_t vb = ((((size_t)nb * KKER + k) * NCH + c) * NDA + dai) * KDIM;
        float* vp = ws + VP_OFF;
        #pragma unroll
        for (int j = 0; j < 8; ++j) {
            int db = db0 + j;
            if (db < KDIM) {
                vp[(vb + db) * 2]     = s * acc[j].x;
                vp[(vb + db) * 2 + 1] = s * acc[j].y;
            }
        }
    }
}

// V[nb][dai][db] = sum_{kc} VP[nb][kc][dai][db]; one block per (nb,dai)
__global__ __launch_bounds__(320) void reduce_V(float* __restrict__ ws) {
    __shared__ float2 Ps[8][KDIM];
    int bid = blockIdx.x;            // nb*NDA + dai
    int nb = bid / NDA, dai = bid - nb * NDA;
    int t = threadIdx.x;
    if (t < 8 * KDIM) {
        int g = t / KDIM, db = t - g * KDIM;
        const float* vp = ws + VP_OFF;
        float sr = 0.f, si = 0.f;
        #pragma unroll
        for (int j = 0; j < 21; ++j) {
            int kc = g + 8 * j;
            size_t idx = ((((size_t)nb * (KKER * NCH) + kc) * NDA + dai) * KDIM + db) * 2;
            sr += vp[idx]; si += vp[idx + 1];
        }
        Ps[g][db] = make_float2(sr, si);
    }
    __syncthreads();
    if (t < KDIM) {
        float sr = 0.f, si = 0.f;
        #pragma unroll
        for (int g = 0; g < 8; ++g) { sr += Ps[g][t].x; si += Ps[g][t].y; }
        size_t o = ((size_t)nb * NDA + dai) * KDIM + t;
        ws[V_OFF + o * 2]     = sr;
        ws[V_OFF + o * 2 + 1] = sr == sr ? si : si;  // plain store
        ws[V_OFF + o * 2 + 1] = si;
    }
}

// Fused mk_U + radix-4 epilogue. Block = (nb, yc); handles YPB consecutive y rows:
//   U[y,db] = sum_dai V[nb][dai][db] e^{+2pi i y (dai-34)/1024}   (computed in LDS)
//   then per row, thread t evaluates x = t+256c via S(i^c z) from four 9-term
//   Horner chains in w=z^4. I = 2*Re(S) - U0r (Hermitian half along x).
#define YPB 2
__global__ __launch_bounds__(256) void litho_fused(const float* __restrict__ ws,
                                                   float* __restrict__ out) {
    __shared__ float2 twl[1024];
    __shared__ float2 Vl[NDA * KDIM];
    __shared__ float2 Ul[YPB][KDIM];
    int bid = blockIdx.x;              // nb*512 + yc
    int yc = bid & 511; int nb = bid >> 9;
    int t = threadIdx.x;
    for (int j = t; j < 1024; j += 256) {
        float s, c;
        sincospif(-2.0f * (float)j * (1.0f / 1024.0f), &s, &c);
        twl[j] = make_float2(c, s);
    }
    const float2* Vg = (const float2*)(ws + V_OFF) + (size_t)nb * NDA * KDIM;
    for (int i = t; i < NDA * KDIM; i += 256) Vl[i] = Vg[i];
    __syncthreads();
    if (t < YPB * KDIM) {
        int yl = t / KDIM, db = t - yl * KDIM;
        int y = yc * YPB + yl;
        float ar = 0.f, ai = 0.f;
        for (int dai = 0; dai < NDA; ++dai) {
            unsigned j = ((unsigned)(y * (dai - 34))) & 1023u;
            float2 cc = twl[j];
            float cr = cc.x, ci = -cc.y;           // e^{+2pi i y da/1024}
            float2 v = Vl[dai * KDIM + db];
            ar = fmaf(v.x, cr, ar); ar = fmaf(-v.y, ci, ar);
            ai = fmaf(v.x, ci, ai); ai = fmaf( v.y, cr, ai);
        }
        Ul[yl][db] = make_float2(ar, ai);
    }
    __syncthreads();
    int n = nb >> 1, br = nb & 1;
    float2 z  = twl[t];              z.y  = -z.y;    // e^{+2pi i t/1024}
    float2 z2 = twl[(2*t) & 1023];   z2.y = -z2.y;
    float2 z3 = twl[(3*t) & 1023];   z3.y = -z3.y;
    float2 w  = twl[(4*t) & 1023];   w.y  = -w.y;    // z^4
    const size_t OS = (size_t)NBATCH * NPIX;
    #pragma unroll
    for (int yl = 0; yl < YPB; ++yl) {
        int y = yc * YPB + yl;
        float2 P0 = Ul[yl][32], P1 = Ul[yl][33], P2 = Ul[yl][34], P3 = make_float2(0.f, 0.f);
        #pragma unroll
        for (int q = 7; q >= 0; --q) {
            P0 = cmadd(P0, w, Ul[yl][4*q]);
            P1 = cmadd(P1, w, Ul[yl][4*q+1]);
            P2 = cmadd(P2, w, Ul[yl][4*q+2]);
            P3 = cmadd(P3, w, Ul[yl][4*q+3]);
        }
        float U0r = Ul[yl][0].x;
        float A1x = P1.x * z.x  - P1.y * z.y,  A1y = P1.x * z.y  + P1.y * z.x;
        float A2x = P2.x * z2.x - P2.y * z2.y;
        float A3x = P3.x * z3.x - P3.y * z3.y, A3y = P3.x * z3.y + P3.y * z3.x;
        float Re4[4];
        Re4[0] = P0.x + A1x + A2x + A3x;
        Re4[1] = P0.x - A1y - A2x + A3y;
        Re4[2] = P0.x - A1x + A2x - A3x;
        Re4[3] = P0.x + A1y - A2x - A3y;
        size_t obase = (size_t)n * NPIX + (size_t)y * WW;
        if (br == 0) {
            #pragma unroll
            for (int c = 0; c < 4; ++c) {
                int x = t + c * 256;
                float If   = fmaf(2.f, Re4[c], -U0r);
                float Imax = If * (1.02f * 1.02f);
                out[0 * OS + obase + x] = sigm(50.f * (If   - 0.225f));
                out[2 * OS + obase + x] = sigm(50.f * (Imax - 0.225f));
                out[3 * OS + obase + x] = If;
                out[5 * OS + obase + x] = Imax;
            }
        } else {
            #pragma unroll
            for (int c = 0; c < 4; ++c) {
                int x = t + c * 256;
                float Id = fmaf(2.f, Re4[c], -U0r);
                out[1 * OS + obase + x] = sigm(50.f * (Id - 0.225f));
                out[4 * OS + obase + x] = Id;
            }
        }
    }
}

extern "C" void kernel_launch(void* const* d_in, const int* in_sizes, int n_in,
                              void* d_out, int out_size, void* d_ws, size_t ws_size,
                              hipStream_t stream) {
    (void)in_sizes; (void)n_in; (void)out_size; (void)ws_size;
    const float* mt  = (const float*)d_in[0];
    const float* kfr = (const float*)d_in[1];
    const float* kfi = (const float*)d_in[2];
    const float* kdr = (const float*)d_in[3];
    const float* kdi = (const float*)d_in[4];
    const float* kfs = (const float*)d_in[5];
    const float* kds = (const float*)d_in[6];
    float* out = (float*)d_out;
    float* ws  = (float*)d_ws;

    hipLaunchKernelGGL(fwd_rows,    dim3(NBATCH * HH),             dim3(320), 0, stream, mt, ws);
    hipLaunchKernelGGL(fwd_cols,    dim3(NBATCH * KDIM),           dim3(320), 0, stream, ws);
    hipLaunchKernelGGL(mk_V,        dim3(NBATCH * 2 * KKER * NCH), dim3(384), 0, stream,
                       ws, kfr, kfi, kdr, kdi, kfs, kds);
    hipLaunchKernelGGL(reduce_V,    dim3(NBATCH * 2 * NDA),        dim3(320), 0, stream, ws);
    hipLaunchKernelGGL(litho_fused, dim3(NBATCH * 2 * 512),        dim3(256), 0, stream, ws, out);
}

// Round 2
// 143.617 us; speedup vs baseline: 1.1579x; 1.0829x over previous
//
#include <hip/hip_runtime.h>
#include <math.h>

#define NBATCH 2
#define HH 1024
#define WW 1024
#define KKER 24
#define KDIM 35
#define NPIX (HH*WW)
#define KSQ (KDIM*KDIM)          // 1225
#define NDA 69                   // da in [-34,34]
#define NTAU 9                   // dai tiles of 8 (last has 5)
#define NFR 18                   // stored row freqs m=0..17 (Hermitian half)

// ---- workspace layout (float offsets) ----
#define G_OFF    0                                       // NBATCH*HH*NFR complex
#define SPEC_OFF (G_OFF + NBATCH*HH*NFR*2)               // NBATCH*35*35 complex
#define VP_OFF   (SPEC_OFF + NBATCH*KSQ*2)               // [nb(4)][k(24)][dai(69)][db(35)] complex
#define V_OFF    (VP_OFF + NBATCH*2*KKER*NDA*KDIM*2)     // [nb][dai][db] complex

__device__ __forceinline__ float2 cmadd(float2 p, float2 w, float2 u) {
    // p*w + u
    return make_float2(fmaf(p.x, w.x, fmaf(-p.y, w.y, u.x)),
                       fmaf(p.x, w.y, fmaf( p.y, w.x, u.y)));
}
__device__ __forceinline__ float sigm(float v) {
    return 1.f / (1.f + expf(-v));
}

// fused: avepool3(zero-pad) + sigmoid + forward DFT along x for m=0..17 (real input:
// G[n,y,-m] = conj(G[n,y,m]), so only half the freqs are computed/stored).
__global__ __launch_bounds__(320) void fwd_rows(const float* __restrict__ mt, float* __restrict__ ws) {
    __shared__ __align__(16) float vs[1024];
    __shared__ float row[1056];          // padded: idx = x + (x>>5) -> kills 4-way bank conflict
    __shared__ float2 twl[1024];
    __shared__ float2 P[16 * NFR];
    int bid = blockIdx.x;            // n*HH + y
    int n = bid >> 10, y = bid & 1023;
    int t = threadIdx.x;
    const float* base = mt + (size_t)n * NPIX;
    if (t < 256) {
        float4 a = ((const float4*)(base + (size_t)y * WW))[t];
        if (y > 0)    { float4 b = ((const float4*)(base + (size_t)(y - 1) * WW))[t];
                        a.x += b.x; a.y += b.y; a.z += b.z; a.w += b.w; }
        if (y < 1023) { float4 b = ((const float4*)(base + (size_t)(y + 1) * WW))[t];
                        a.x += b.x; a.y += b.y; a.z += b.z; a.w += b.w; }
        ((float4*)vs)[t] = a;
    }
    for (int j = t; j < 1024; j += 320) {
        float s, c;
        sincospif(-2.0f * (float)j * (1.0f / 1024.0f), &s, &c);
        twl[j] = make_float2(c, s);      // e^{-2 pi i j / 1024}
    }
    __syncthreads();
    for (int x = t; x < 1024; x += 320) {
        float s = vs[x];
        if (x > 0)    s += vs[x - 1];
        if (x < 1023) s += vs[x + 1];
        s *= (1.0f / 9.0f);
        row[x + (x >> 5)] = sigm(4.0f * (s - 0.5f));
    }
    __syncthreads();
    if (t < 16 * NFR) {
        int q = t / NFR, m = t - q * NFR;   // q in [0,16), m in [0,18)
        float2 cm = twl[m];                 // e^{-2pi i m/1024}
        float ar = 0.f, ai = 0.f;
        #pragma unroll
        for (int sc = 0; sc < 2; ++sc) {
            int xs = q * 64 + sc * 32;
            unsigned j0 = ((unsigned)(m * xs)) & 1023u;
            float2 wv = twl[j0];               // exact resync
            float wr = wv.x, wi = wv.y;
            int rb = xs + (xs >> 5);
            #pragma unroll
            for (int i = 0; i < 32; ++i) {
                float val = row[rb + i];
                ar = fmaf(val, wr, ar);
                ai = fmaf(val, wi, ai);
                float nwr = fmaf(wr, cm.x, -wi * cm.y);
                float nwi = fmaf(wr, cm.y,  wi * cm.x);
                wr = nwr; wi = nwi;
            }
        }
        P[t] = make_float2(ar, ai);
    }
    __syncthreads();
    if (t < NFR) {
        float gr = 0.f, gi = 0.f;
        #pragma unroll
        for (int q = 0; q < 16; ++q) {
            gr += P[q * NFR + t].x;
            gi += P[q * NFR + t].y;
        }
        float2* Gp = (float2*)(ws + G_OFF) + (size_t)(n * HH + y) * NFR + t;
        *Gp = make_float2(gr, gi);
    }
}

// forward DFT along y for the half-plane b>=17; the other half follows by Hermitian
// symmetry of the 2D spectrum of a real image: spec[34-a][34-b] = conj(spec[a][b]).
__global__ __launch_bounds__(320) void fwd_cols(float* __restrict__ ws) {
    __shared__ float2 twl[1024];
    __shared__ float2 P[16 * NFR];
    int bid = blockIdx.x;            // n*KDIM + a
    int n = bid / KDIM, a = bid - n * KDIM;
    int t = threadIdx.x;
    for (int j = t; j < 1024; j += 320) {
        float s, c;
        sincospif(-2.0f * (float)j * (1.0f / 1024.0f), &s, &c);
        twl[j] = make_float2(c, s);
    }
    __syncthreads();
    if (t < 16 * NFR) {
        int g = t / NFR, mb = t - g * NFR;   // g in [0,16) y-chunks, mb = b-17 in [0,18)
        int ma = a - 17;
        int y0 = g * 64;
        const float2* Gp = (const float2*)(ws + G_OFF) + (size_t)n * HH * NFR + mb;
        float ar = 0.f, ai = 0.f;
        for (int i = 0; i < 64; ++i) {
            int y = y0 + i;
            unsigned j = ((unsigned)(ma * y)) & 1023u;
            float2 g2 = Gp[(size_t)y * NFR];
            float2 cc = twl[j];
            ar = fmaf(g2.x, cc.x, ar); ar = fmaf(-g2.y, cc.y, ar);
            ai = fmaf(g2.x, cc.y, ai); ai = fmaf( g2.y, cc.x, ai);
        }
        P[t] = make_float2(ar, ai);
    }
    __syncthreads();
    if (t < NFR) {
        float sr = 0.f, si = 0.f;
        #pragma unroll
        for (int g = 0; g < 16; ++g) { sr += P[g * NFR + t].x; si += P[g * NFR + t].y; }
        float2* Sp = (float2*)(ws + SPEC_OFF) + (size_t)n * KSQ;
        Sp[a * KDIM + (17 + t)] = make_float2(sr, si);
        if (t > 0)
            Sp[(34 - a) * KDIM + (17 - t)] = make_float2(sr, -si);  // Hermitian mirror
    }
}

// 2D autocorrelation V[da,db] = sum_{ap,bp} X[ap+da, bp+db] * conj(X[ap,bp]).
// Blocks tile dai into NTAU tiles of 8, so the ap loop only covers the valid
// overlap window (width 8..35) instead of all 35 rows (kills the 2x zero-row waste).
// Wave = one db-octet (uniform bp trip). Lane = (dai8, apSlot): 8 lags x 8 ap
// phases; per-lane exec mask enforces ap+da in [0,35); sliding-window inner loop
// (8 db per lane); shfl_xor reduce over the 8 apSlots at the end.
#define VCOLS 43    // cols 0..34 valid, 35..42 zero pad
__global__ __launch_bounds__(320) void mk_V(float* __restrict__ ws,
        const float* __restrict__ kfr, const float* __restrict__ kfi,
        const float* __restrict__ kdr, const float* __restrict__ kdi,
        const float* __restrict__ kfs, const float* __restrict__ kds) {
    __shared__ float2 Xp[KDIM * VCOLS];   // 12 KB
    int bid = blockIdx.x;
    int tau = bid % NTAU; int r = bid / NTAU;
    int k = r % KKER; r /= KKER;
    int br = r & 1; int n = r >> 1;
    int t = threadIdx.x;
    for (int i = t; i < KDIM * VCOLS; i += 320) Xp[i] = make_float2(0.f, 0.f);
    __syncthreads();
    const float* kr = (br ? kdr : kfr) + (size_t)k * KSQ;
    const float* ki = (br ? kdi : kfi) + (size_t)k * KSQ;
    const float* sp = ws + SPEC_OFF + (size_t)n * KSQ * 2;
    for (int i = t; i < KSQ; i += 320) {
        int a = i / KDIM, b = i - a * KDIM;
        float srr = sp[2*i], sii = sp[2*i + 1];
        float krr = kr[i], kii = ki[i];
        Xp[a * VCOLS + b] = make_float2(srr * krr - sii * kii, srr * kii + sii * krr);
    }
    __syncthreads();
    const float INVN = 0x1p-40f;
    float s = (br ? kds[k] * (0.98f * 0.98f) : kfs[k]) * INVN;

    int dbg  = t >> 6;            // wave id = db-octet, 0..4
    int lane = t & 63;
    int apSlot = lane & 7;
    int dai8   = lane >> 3;
    int dai = tau * 8 + dai8;
    int da  = dai - 34;
    int db0 = dbg * 8;
    int nbp = KDIM - db0;         // 35,27,19,11,3 (wave-uniform)

    int daiHi = tau * 8 + 7; if (daiHi > NDA - 1) daiHi = NDA - 1;
    int daLo = tau * 8 - 34, daHi = daiHi - 34;
    int apLo = (-daHi > 0) ? -daHi : 0;
    int apHi = KDIM - daLo; if (apHi > KDIM) apHi = KDIM;   // exclusive

    float2 acc[8];
    #pragma unroll
    for (int j = 0; j < 8; ++j) acc[j] = make_float2(0.f, 0.f);

    for (int ap = apLo + apSlot; ap < apHi; ap += 8) {
        bool act = ((unsigned)(ap + da) < (unsigned)KDIM) && (dai < NDA);
        if (act) {
            const float2* rx = Xp + (ap + da) * VCOLS + db0;
            const float2* ry = Xp + ap * VCOLS;
            float2 w[8];
            #pragma unroll
            for (int j = 0; j < 8; ++j) w[j] = rx[j];
            int bp = 0;
            for (; bp + 8 <= nbp; bp += 8) {
                #pragma unroll
                for (int u = 0; u < 8; ++u) {
                    float2 yv = ry[bp + u];
                    #pragma unroll
                    for (int j = 0; j < 8; ++j) {
                        acc[j].x = fmaf(w[j].x, yv.x, acc[j].x);
                        acc[j].x = fmaf(w[j].y, yv.y, acc[j].x);
                        acc[j].y = fmaf(w[j].y, yv.x, acc[j].y);
                        acc[j].y = fmaf(-w[j].x, yv.y, acc[j].y);
                    }
                    #pragma unroll
                    for (int j = 0; j < 7; ++j) w[j] = w[j + 1];
                    w[7] = rx[bp + u + 8];
                }
            }
            for (; bp < nbp; ++bp) {
                float2 yv = ry[bp];
                #pragma unroll
                for (int j = 0; j < 8; ++j) {
                    acc[j].x = fmaf(w[j].x, yv.x, acc[j].x);
                    acc[j].x = fmaf(w[j].y, yv.y, acc[j].x);
                    acc[j].y = fmaf(w[j].y, yv.x, acc[j].y);
                    acc[j].y = fmaf(-w[j].x, yv.y, acc[j].y);
                }
                #pragma unroll
                for (int j = 0; j < 7; ++j) w[j] = w[j + 1];
                w[7] = rx[bp + 8];
            }
        }
    }
    // reduce the 8 apSlot partials (lanes differing in bits 0..2 only)
    #pragma unroll
    for (int j = 0; j < 8; ++j) {
        acc[j].x += __shfl_xor(acc[j].x, 1); acc[j].y += __shfl_xor(acc[j].y, 1);
        acc[j].x += __shfl_xor(acc[j].x, 2); acc[j].y += __shfl_xor(acc[j].y, 2);
        acc[j].x += __shfl_xor(acc[j].x, 4); acc[j].y += __shfl_xor(acc[j].y, 4);
    }
    if (apSlot == 0 && dai < NDA) {
        int nb = n * 2 + br;
        float2* vp = (float2*)(ws + VP_OFF);
        size_t vb = (((size_t)nb * KKER + k) * NDA + dai) * KDIM;
        #pragma unroll
        for (int j = 0; j < 8; ++j) {
            int db = db0 + j;
            if (db < KDIM)
                vp[vb + db] = make_float2(s * acc[j].x, s * acc[j].y);
        }
    }
}

// V[nb][dai][db] = sum_k VP[nb][k][dai][db]; one block per (nb,dai)
__global__ __launch_bounds__(64) void reduce_V(float* __restrict__ ws) {
    int bid = blockIdx.x;            // nb*NDA + dai
    int nb = bid / NDA, dai = bid - nb * NDA;
    int t = threadIdx.x;
    if (t < KDIM) {
        const float2* vp = (const float2*)(ws + VP_OFF);
        float sr = 0.f, si = 0.f;
        #pragma unroll
        for (int k = 0; k < KKER; ++k) {
            float2 v = vp[(((size_t)nb * KKER + k) * NDA + dai) * KDIM + t];
            sr += v.x; si += v.y;
        }
        ((float2*)(ws + V_OFF))[((size_t)nb * NDA + dai) * KDIM + t] = make_float2(sr, si);
    }
}

// Fused mk_U + radix-4 epilogue. Block = (nb, yc); handles YPB consecutive y rows:
//   U[y,db] = sum_dai V[nb][dai][db] e^{+2pi i y (dai-34)/1024}   (computed in LDS)
//   then per row, thread t evaluates x = t+256c via S(i^c z) from four 9-term
//   Horner chains in w=z^4. I = 2*Re(S) - U0r (Hermitian half along x).
#define YPB 2
__global__ __launch_bounds__(256) void litho_fused(const float* __restrict__ ws,
                                                   float* __restrict__ out) {
    __shared__ float2 twl[1024];
    __shared__ float2 Vl[NDA * KDIM];
    __shared__ float2 Ul[YPB][KDIM];
    int bid = blockIdx.x;              // nb*512 + yc
    int yc = bid & 511; int nb = bid >> 9;
    int t = threadIdx.x;
    for (int j = t; j < 1024; j += 256) {
        float s, c;
        sincospif(-2.0f * (float)j * (1.0f / 1024.0f), &s, &c);
        twl[j] = make_float2(c, s);
    }
    const float2* Vg = (const float2*)(ws + V_OFF) + (size_t)nb * NDA * KDIM;
    for (int i = t; i < NDA * KDIM; i += 256) Vl[i] = Vg[i];
    __syncthreads();
    if (t < YPB * KDIM) {
        int yl = t / KDIM, db = t - yl * KDIM;
        int y = yc * YPB + yl;
        float ar = 0.f, ai = 0.f;
        for (int dai = 0; dai < NDA; ++dai) {
            unsigned j = ((unsigned)(y * (dai - 34))) & 1023u;
            float2 cc = twl[j];
            float cr = cc.x, ci = -cc.y;           // e^{+2pi i y da/1024}
            float2 v = Vl[dai * KDIM + db];
            ar = fmaf(v.x, cr, ar); ar = fmaf(-v.y, ci, ar);
            ai = fmaf(v.x, ci, ai); ai = fmaf( v.y, cr, ai);
        }
        Ul[yl][db] = make_float2(ar, ai);
    }
    __syncthreads();
    int n = nb >> 1, br = nb & 1;
    float2 z  = twl[t];              z.y  = -z.y;    // e^{+2pi i t/1024}
    float2 z2 = twl[(2*t) & 1023];   z2.y = -z2.y;
    float2 z3 = twl[(3*t) & 1023];   z3.y = -z3.y;
    float2 w  = twl[(4*t) & 1023];   w.y  = -w.y;    // z^4
    const size_t OS = (size_t)NBATCH * NPIX;
    #pragma unroll
    for (int yl = 0; yl < YPB; ++yl) {
        int y = yc * YPB + yl;
        float2 P0 = Ul[yl][32], P1 = Ul[yl][33], P2 = Ul[yl][34], P3 = make_float2(0.f, 0.f);
        #pragma unroll
        for (int q = 7; q >= 0; --q) {
            P0 = cmadd(P0, w, Ul[yl][4*q]);
            P1 = cmadd(P1, w, Ul[yl][4*q+1]);
            P2 = cmadd(P2, w, Ul[yl][4*q+2]);
            P3 = cmadd(P3, w, Ul[yl][4*q+3]);
        }
        float U0r = Ul[yl][0].x;
        float A1x = P1.x * z.x  - P1.y * z.y,  A1y = P1.x * z.y  + P1.y * z.x;
        float A2x = P2.x * z2.x - P2.y * z2.y;
        float A3x = P3.x * z3.x - P3.y * z3.y, A3y = P3.x * z3.y + P3.y * z3.x;
        float Re4[4];
        Re4[0] = P0.x + A1x + A2x + A3x;
        Re4[1] = P0.x - A1y - A2x + A3y;
        Re4[2] = P0.x - A1x + A2x - A3x;
        Re4[3] = P0.x + A1y - A2x - A3y;
        size_t obase = (size_t)n * NPIX + (size_t)y * WW;
        if (br == 0) {
            #pragma unroll
            for (int c = 0; c < 4; ++c) {
                int x = t + c * 256;
                float If   = fmaf(2.f, Re4[c], -U0r);
                float Imax = If * (1.02f * 1.02f);
                out[0 * OS + obase + x] = sigm(50.f * (If   - 0.225f));
                out[2 * OS + obase + x] = sigm(50.f * (Imax - 0.225f));
                out[3 * OS + obase + x] = If;
                out[5 * OS + obase + x] = Imax;
            }
        } else {
            #pragma unroll
            for (int c = 0; c < 4; ++c) {
                int x = t + c * 256;
                float Id = fmaf(2.f, Re4[c], -U0r);
                out[1 * OS + obase + x] = sigm(50.f * (Id - 0.225f));
                out[4 * OS + obase + x] = Id;
            }
        }
    }
}

extern "C" void kernel_launch(void* const* d_in, const int* in_sizes, int n_in,
                              void* d_out, int out_size, void* d_ws, size_t ws_size,
                              hipStream_t stream) {
    (void)in_sizes; (void)n_in; (void)out_size; (void)ws_size;
    const float* mt  = (const float*)d_in[0];
    const float* kfr = (const float*)d_in[1];
    const float* kfi = (const float*)d_in[2];
    const float* kdr = (const float*)d_in[3];
    const float* kdi = (const float*)d_in[4];
    const float* kfs = (const float*)d_in[5];
    const float* kds = (const float*)d_in[6];
    float* out = (float*)d_out;
    float* ws  = (float*)d_ws;

    hipLaunchKernelGGL(fwd_rows,    dim3(NBATCH * HH),              dim3(320), 0, stream, mt, ws);
    hipLaunchKernelGGL(fwd_cols,    dim3(NBATCH * KDIM),            dim3(320), 0, stream, ws);
    hipLaunchKernelGGL(mk_V,        dim3(NBATCH * 2 * KKER * NTAU), dim3(320), 0, stream,
                       ws, kfr, kfi, kdr, kdi, kfs, kds);
    hipLaunchKernelGGL(reduce_V,    dim3(NBATCH * 2 * NDA),         dim3(64),  0, stream, ws);
    hipLaunchKernelGGL(litho_fused, dim3(NBATCH * 2 * 512),         dim3(256), 0, stream, ws, out);
}